// Round 1
// baseline (3995.943 us; speedup 1.0000x reference)
//
#include <hip/hip_runtime.h>
#include <math.h>

#define EPS 1e-8f

// ---------------------------------------------------------------------------
// Transpose conv1 weights: wt1[k][n] = w1[n][k]; k in [0,81), n in [0,256)
__global__ void k_tw1(const float* __restrict__ w1, float* __restrict__ wt1) {
    int idx = blockIdx.x * 256 + threadIdx.x;          // 81*256 = 20736
    if (idx >= 81 * 256) return;
    int k = idx >> 8, n = idx & 255;
    wt1[idx] = w1[n * 81 + k];
}

// Transpose conv2 weights: wt2[k][oc], k = q*256 + ic (q = kh*9+kw)
// src pc_w[oc][ic][kh][kw] = pw[oc*20736 + ic*81 + q]
__global__ void k_tw2(const float* __restrict__ pw, float* __restrict__ wt2) {
    int idx = blockIdx.x * 256 + threadIdx.x;          // 20736*256
    int k = idx >> 8, oc = idx & 255;
    int q = k >> 8, ic = k & 255;
    wt2[idx] = pw[oc * 20736 + ic * 81 + q];
}

// Initialize h2[b][c][sp] with conv2 bias[c] (split-K atomics accumulate on top)
__global__ void k_init_h2(const float* __restrict__ pb, float* __restrict__ h2) {
    int idx = blockIdx.x * 256 + threadIdx.x;          // 512*9216
    int c = (idx % 9216) / 36;
    h2[idx] = pb[c];
}

// ---------------------------------------------------------------------------
// conv1 as GEMM: M=512*400 (m=b*400+oh*20+ow), N=256, K=81 (k=kh*9+kw)
// BM=64 BN=256 BK=16, 256 threads, 8x8 per thread. Epilogue: +bias, ReLU,
// write h1 NHWC: h1[m*256 + n].
__global__ __launch_bounds__(256) void k_conv1(const float* __restrict__ x,
                                               const float* __restrict__ wt1,
                                               const float* __restrict__ b1,
                                               float* __restrict__ h1) {
    __shared__ float As[16][68];
    __shared__ float Bs[16][260];
    const int tid = threadIdx.x;
    const int m0 = blockIdx.x * 64;
    const int tr = tid >> 5, tc = tid & 31;
    float acc[8][8];
#pragma unroll
    for (int i = 0; i < 8; ++i)
#pragma unroll
        for (int j = 0; j < 8; ++j) acc[i][j] = 0.f;

    // A-load coordinates (fixed per thread)
    const int m_l = tid >> 2;
    const int k_lb = (tid & 3) * 4;
    {
    }
    const int m = m0 + m_l;
    const int b = m / 400, sp = m % 400;
    const int oh = sp / 20, ow = sp % 20;
    const float* xb = x + b * 784 + oh * 28 + ow;

    for (int k0 = 0; k0 < 81; k0 += 16) {
        // A: 64x16, 4 scalars per thread (k-contiguous)
#pragma unroll
        for (int j = 0; j < 4; ++j) {
            int k = k0 + k_lb + j;
            float v = 0.f;
            if (k < 81) { int kh = k / 9, kw = k % 9; v = xb[kh * 28 + kw]; }
            As[k_lb + j][m_l] = v;
        }
        // B: 16x256, 16 floats per thread
        {
            int r = tid >> 4, cb = (tid & 15) * 16;
            int k = k0 + r;
            if (k < 81) {
                const float4* src = (const float4*)(wt1 + k * 256 + cb);
#pragma unroll
                for (int j = 0; j < 4; ++j) *(float4*)(&Bs[r][cb + j * 4]) = src[j];
            } else {
#pragma unroll
                for (int j = 0; j < 16; ++j) Bs[r][cb + j] = 0.f;
            }
        }
        __syncthreads();
#pragma unroll
        for (int kk = 0; kk < 16; ++kk) {
            float a[8], bb[8];
            *(float4*)a       = *(const float4*)(&As[kk][tr * 8]);
            *(float4*)(a + 4) = *(const float4*)(&As[kk][tr * 8 + 4]);
            *(float4*)bb       = *(const float4*)(&Bs[kk][tc * 8]);
            *(float4*)(bb + 4) = *(const float4*)(&Bs[kk][tc * 8 + 4]);
#pragma unroll
            for (int i = 0; i < 8; ++i)
#pragma unroll
                for (int j = 0; j < 8; ++j) acc[i][j] += a[i] * bb[j];
        }
        __syncthreads();
    }
    float bias[8];
    *(float4*)bias       = *(const float4*)(b1 + tc * 8);
    *(float4*)(bias + 4) = *(const float4*)(b1 + tc * 8 + 4);
#pragma unroll
    for (int i = 0; i < 8; ++i) {
        int mm = m0 + tr * 8 + i;
        float* dst = h1 + (size_t)mm * 256 + tc * 8;
        float o4[8];
#pragma unroll
        for (int j = 0; j < 8; ++j) {
            float v = acc[i][j] + bias[j];
            o4[j] = v > 0.f ? v : 0.f;
        }
        *(float4*)dst       = *(float4*)o4;
        *(float4*)(dst + 4) = *(float4*)(o4 + 4);
    }
}

// ---------------------------------------------------------------------------
// conv2 as GEMM: M=512*36 (m=b*36+oh*6+ow), N=256 (oc), K=20736 (k=q*256+ic)
// A[m][k] = h1 NHWC [((b*20 + 2*oh+kh)*20 + 2*ow+kw)*256 + ic]
// split-K = 4 (blockIdx.y), atomicAdd into bias-initialized h2[b][oc][sp]
__global__ __launch_bounds__(256) void k_conv2(const float* __restrict__ h1,
                                               const float* __restrict__ wt2,
                                               float* __restrict__ h2) {
    __shared__ float As[16][68];
    __shared__ float Bs[16][260];
    const int tid = threadIdx.x;
    const int m0 = blockIdx.x * 64;
    const int ks = blockIdx.y * 5184;
    const int tr = tid >> 5, tc = tid & 31;
    float acc[8][8];
#pragma unroll
    for (int i = 0; i < 8; ++i)
#pragma unroll
        for (int j = 0; j < 8; ++j) acc[i][j] = 0.f;

    const int m_l = tid >> 2;
    const int k_lb = (tid & 3) * 4;
    const int m = m0 + m_l;
    const int b = m / 36, sp = m % 36;
    const int oh = sp / 6, ow = sp % 6;
    const float* h1b = h1 + ((size_t)(b * 20 + 2 * oh) * 20 + 2 * ow) * 256;

    for (int k0 = ks; k0 < ks + 5184; k0 += 16) {
        {
            int k = k0 + k_lb;
            int q = k >> 8, ic = k & 255;
            int kh = q / 9, kw = q % 9;
            float4 v = *(const float4*)(h1b + (kh * 20 + kw) * 256 + ic);
            As[k_lb + 0][m_l] = v.x;
            As[k_lb + 1][m_l] = v.y;
            As[k_lb + 2][m_l] = v.z;
            As[k_lb + 3][m_l] = v.w;
        }
        {
            int r = tid >> 4, cb = (tid & 15) * 16;
            const float4* src = (const float4*)(wt2 + (size_t)(k0 + r) * 256 + cb);
#pragma unroll
            for (int j = 0; j < 4; ++j) *(float4*)(&Bs[r][cb + j * 4]) = src[j];
        }
        __syncthreads();
#pragma unroll
        for (int kk = 0; kk < 16; ++kk) {
            float a[8], bb[8];
            *(float4*)a       = *(const float4*)(&As[kk][tr * 8]);
            *(float4*)(a + 4) = *(const float4*)(&As[kk][tr * 8 + 4]);
            *(float4*)bb       = *(const float4*)(&Bs[kk][tc * 8]);
            *(float4*)(bb + 4) = *(const float4*)(&Bs[kk][tc * 8 + 4]);
#pragma unroll
            for (int i = 0; i < 8; ++i)
#pragma unroll
                for (int j = 0; j < 8; ++j) acc[i][j] += a[i] * bb[j];
        }
        __syncthreads();
    }
#pragma unroll
    for (int i = 0; i < 8; ++i) {
        int mm = m0 + tr * 8 + i;
        int b2 = mm / 36, sp2 = mm % 36;
        float* dst = h2 + (size_t)b2 * 9216 + sp2;
#pragma unroll
        for (int j = 0; j < 8; ++j) atomicAdd(dst + (tc * 8 + j) * 36, acc[i][j]);
    }
}

// ---------------------------------------------------------------------------
// Primary-capsule squash, in place on h2: groups of 8 consecutive floats.
__global__ void k_squash(float* __restrict__ h2) {
    int idx = blockIdx.x * 256 + threadIdx.x;          // 512*1152 capsules
    if (idx >= 512 * 1152) return;
    float* p = h2 + (size_t)idx * 8;
    float4 a = *(float4*)p, c = *(float4*)(p + 4);
    float n2 = a.x * a.x + a.y * a.y + a.z * a.z + a.w * a.w +
               c.x * c.x + c.y * c.y + c.z * c.z + c.w * c.w;
    float n = sqrtf(n2);
    float s = n2 / (1.f + n2) / (n + EPS);
    a.x *= s; a.y *= s; a.z *= s; a.w *= s;
    c.x *= s; c.y *= s; c.z *= s; c.w *= s;
    *(float4*)p = a;
    *(float4*)(p + 4) = c;
}

// ---------------------------------------------------------------------------
// Dynamic routing, one block per batch element. 320 threads = 10 o-caps x 32
// lanes. x_hat recomputed from caps_w (streamed 3x per block); b_logits in LDS.
__global__ __launch_bounds__(320) void k_routing(const float* __restrict__ u,
                                                 const float* __restrict__ cw,
                                                 float* __restrict__ out) {
    __shared__ float bl[10][1152];
    __shared__ float sv[10][16];
    __shared__ float stats_m[32], stats_si[32];
    __shared__ float scale_sh[10];
    const int t = threadIdx.x;
    const int b = blockIdx.x;
    const int o = t >> 5, lane = t & 31;
    const float* ub = u + (size_t)b * 9216;
    float v_loc[16];
#pragma unroll
    for (int d = 0; d < 16; ++d) v_loc[d] = 0.f;

    for (int pass = 0; pass < 3; ++pass) {
        float s_loc[16];
#pragma unroll
        for (int d = 0; d < 16; ++d) s_loc[d] = 0.f;
        if (pass > 0) {
#pragma unroll
            for (int d = 0; d < 16; ++d) v_loc[d] = sv[o][d];
        }
        for (int chunk = 0; chunk < 36; ++chunk) {
            int i = chunk * 32 + lane;
            float ui[8];
            *(float4*)ui       = *(const float4*)(ub + i * 8);
            *(float4*)(ui + 4) = *(const float4*)(ub + i * 8 + 4);
            const float4* wp = (const float4*)(cw + (size_t)(o * 1152 + i) * 128);
            float xh[16];
#pragma unroll
            for (int d = 0; d < 16; ++d) {
                float4 w0 = wp[d * 2], w1 = wp[d * 2 + 1];
                xh[d] = w0.x * ui[0] + w0.y * ui[1] + w0.z * ui[2] + w0.w * ui[3] +
                        w1.x * ui[4] + w1.y * ui[5] + w1.z * ui[6] + w1.w * ui[7];
            }
            float c;
            if (pass > 0) {
                float dot = 0.f;
#pragma unroll
                for (int d = 0; d < 16; ++d) dot += v_loc[d] * xh[d];
                float blv = (pass == 1) ? dot : (bl[o][i] + dot);
                bl[o][i] = blv;
                __syncthreads();
                if (t < 32) {
                    int i2 = chunk * 32 + t;
                    float mx = bl[0][i2];
#pragma unroll
                    for (int oo = 1; oo < 10; ++oo) mx = fmaxf(mx, bl[oo][i2]);
                    float se = 0.f;
#pragma unroll
                    for (int oo = 0; oo < 10; ++oo) se += expf(bl[oo][i2] - mx);
                    stats_m[t] = mx;
                    stats_si[t] = 1.f / se;
                }
                __syncthreads();
                c = expf(blv - stats_m[lane]) * stats_si[lane];
            } else {
                c = 0.1f;
            }
#pragma unroll
            for (int d = 0; d < 16; ++d) s_loc[d] += c * xh[d];
        }
        // reduce s over the 32 lanes that share an o
#pragma unroll
        for (int off = 16; off > 0; off >>= 1) {
#pragma unroll
            for (int d = 0; d < 16; ++d) s_loc[d] += __shfl_down(s_loc[d], off, 32);
        }
        if (lane == 0) {
#pragma unroll
            for (int d = 0; d < 16; ++d) sv[o][d] = s_loc[d];
        }
        __syncthreads();
        if (pass < 2) {
            if (t < 10) {
                float n2 = 0.f;
#pragma unroll
                for (int d = 0; d < 16; ++d) n2 += sv[t][d] * sv[t][d];
                float n = sqrtf(n2);
                scale_sh[t] = n2 / (1.f + n2) / (n + EPS);
            }
            __syncthreads();
            if (t < 160) sv[t >> 4][t & 15] *= scale_sh[t >> 4];
            __syncthreads();
        } else {
            if (t < 10) {
                float n2 = 0.f;
#pragma unroll
                for (int d = 0; d < 16; ++d) n2 += sv[t][d] * sv[t][d];
                float n = sqrtf(n2);
                out[b * 10 + t] = (n2 / (1.f + n2)) * (n / (n + EPS));
            }
        }
    }
}

// ---------------------------------------------------------------------------
extern "C" void kernel_launch(void* const* d_in, const int* in_sizes, int n_in,
                              void* d_out, int out_size, void* d_ws, size_t ws_size,
                              hipStream_t stream) {
    const float* x  = (const float*)d_in[0];   // [512,1,28,28]
    const float* w1 = (const float*)d_in[1];   // [256,1,9,9]
    const float* b1 = (const float*)d_in[2];   // [256]
    const float* pw = (const float*)d_in[3];   // [256,256,9,9]
    const float* pb = (const float*)d_in[4];   // [256]
    const float* cw = (const float*)d_in[5];   // [10,1152,16,8]
    float* out = (float*)d_out;                // [512,10]

    float* ws  = (float*)d_ws;
    float* h1  = ws;                 // 52,428,800 floats (NHWC conv1 out)
    float* h2  = h1 + 52428800;      //  4,718,592 floats (conv2 out -> u in place)
    float* wt1 = h2 + 4718592;       //     20,736 floats
    float* wt2 = wt1 + 20736;        //  5,308,416 floats
    // total ~250 MB of ws

    k_tw1<<<81, 256, 0, stream>>>(w1, wt1);
    k_tw2<<<20736, 256, 0, stream>>>(pw, wt2);
    k_init_h2<<<18432, 256, 0, stream>>>(pb, h2);
    k_conv1<<<3200, 256, 0, stream>>>(x, wt1, b1, h1);
    k_conv2<<<dim3(288, 4), 256, 0, stream>>>(h1, wt2, h2);
    k_squash<<<2304, 256, 0, stream>>>(h2);
    k_routing<<<512, 320, 0, stream>>>(h2, cw, out);
}

// Round 2
// 1788.096 us; speedup vs baseline: 2.2347x; 2.2347x over previous
//
#include <hip/hip_runtime.h>
#include <hip/hip_bf16.h>
#include <math.h>

#define EPS 1e-8f

typedef __attribute__((ext_vector_type(8))) short bf16x8;
typedef __attribute__((ext_vector_type(4))) float f32x4;

__device__ static inline unsigned short f2bf(float f) {
    __hip_bfloat16 h = __float2bfloat16(f);
    return *reinterpret_cast<unsigned short*>(&h);
}

__device__ static inline void gld_lds16(const void* g, void* l) {
    __builtin_amdgcn_global_load_lds((const __attribute__((address_space(1))) void*)g,
                                     (__attribute__((address_space(3))) void*)l, 16, 0, 0);
}

// ---------------------------------------------------------------------------
// Transpose conv1 weights: wt1[k][n] = w1[n][k]; k in [0,81), n in [0,256)
__global__ void k_tw1(const float* __restrict__ w1, float* __restrict__ wt1) {
    int idx = blockIdx.x * 256 + threadIdx.x;
    if (idx >= 81 * 256) return;
    int k = idx >> 8, n = idx & 255;
    wt1[idx] = w1[n * 81 + k];
}

// conv2 weights -> bf16, layout wt2t[oc][k] with k = q*256+ic (q=kh*9+kw)
// src pc_w[oc][ic][kh][kw] = pw[oc*20736 + ic*81 + q]
__global__ void k_tw2(const float* __restrict__ pw, unsigned short* __restrict__ wt2t) {
    int idx = blockIdx.x * 256 + threadIdx.x;          // 256*20736
    int oc = idx / 20736, k = idx % 20736;
    int q = k >> 8, ic = k & 255;
    wt2t[idx] = f2bf(pw[oc * 20736 + ic * 81 + q]);
}

// Initialize h2[b][c][sp] with conv2 bias[c] (split-K atomics accumulate on top)
__global__ void k_init_h2(const float* __restrict__ pb, float* __restrict__ h2) {
    int idx = blockIdx.x * 256 + threadIdx.x;          // 512*9216
    int c = (idx % 9216) / 36;
    h2[idx] = pb[c];
}

// ---------------------------------------------------------------------------
// conv1 as fp32 GEMM: M=512*400, N=256, K=81. Output h1 NHWC in bf16.
__global__ __launch_bounds__(256) void k_conv1(const float* __restrict__ x,
                                               const float* __restrict__ wt1,
                                               const float* __restrict__ b1,
                                               unsigned short* __restrict__ h1) {
    __shared__ float As[16][68];
    __shared__ float Bs[16][260];
    const int tid = threadIdx.x;
    const int m0 = blockIdx.x * 64;
    const int tr = tid >> 5, tc = tid & 31;
    float acc[8][8];
#pragma unroll
    for (int i = 0; i < 8; ++i)
#pragma unroll
        for (int j = 0; j < 8; ++j) acc[i][j] = 0.f;

    const int m_l = tid >> 2;
    const int k_lb = (tid & 3) * 4;
    const int m = m0 + m_l;
    const int b = m / 400, sp = m % 400;
    const int oh = sp / 20, ow = sp % 20;
    const float* xb = x + b * 784 + oh * 28 + ow;

    for (int k0 = 0; k0 < 81; k0 += 16) {
#pragma unroll
        for (int j = 0; j < 4; ++j) {
            int k = k0 + k_lb + j;
            float v = 0.f;
            if (k < 81) { int kh = k / 9, kw = k % 9; v = xb[kh * 28 + kw]; }
            As[k_lb + j][m_l] = v;
        }
        {
            int r = tid >> 4, cb = (tid & 15) * 16;
            int k = k0 + r;
            if (k < 81) {
                const float4* src = (const float4*)(wt1 + k * 256 + cb);
#pragma unroll
                for (int j = 0; j < 4; ++j) *(float4*)(&Bs[r][cb + j * 4]) = src[j];
            } else {
#pragma unroll
                for (int j = 0; j < 16; ++j) Bs[r][cb + j] = 0.f;
            }
        }
        __syncthreads();
#pragma unroll
        for (int kk = 0; kk < 16; ++kk) {
            float a[8], bb[8];
            *(float4*)a       = *(const float4*)(&As[kk][tr * 8]);
            *(float4*)(a + 4) = *(const float4*)(&As[kk][tr * 8 + 4]);
            *(float4*)bb       = *(const float4*)(&Bs[kk][tc * 8]);
            *(float4*)(bb + 4) = *(const float4*)(&Bs[kk][tc * 8 + 4]);
#pragma unroll
            for (int i = 0; i < 8; ++i)
#pragma unroll
                for (int j = 0; j < 8; ++j) acc[i][j] += a[i] * bb[j];
        }
        __syncthreads();
    }
    float bias[8];
    *(float4*)bias       = *(const float4*)(b1 + tc * 8);
    *(float4*)(bias + 4) = *(const float4*)(b1 + tc * 8 + 4);
#pragma unroll
    for (int i = 0; i < 8; ++i) {
        int mm = m0 + tr * 8 + i;
        unsigned short o16[8];
#pragma unroll
        for (int j = 0; j < 8; ++j) {
            float v = acc[i][j] + bias[j];
            o16[j] = f2bf(v > 0.f ? v : 0.f);
        }
        *(uint4*)(h1 + (size_t)mm * 256 + tc * 8) = *(uint4*)o16;
    }
}

// ---------------------------------------------------------------------------
// conv2 as bf16 MFMA GEMM: M=18432 (b*36+sp), N=256 (oc), K=20736 (q*256+ic)
// BM=128 BN=128 BK=64, 4 waves (each 64x64 via 4x4 mfma 16x16x32), split-K=2.
// Staging via global_load_lds w16 with XOR chunk swizzle on global addresses.
__global__ __launch_bounds__(256) void k_conv2(const unsigned short* __restrict__ h1,
                                               const unsigned short* __restrict__ wt2t,
                                               float* __restrict__ h2) {
    __shared__ short Asm[128 * 64];   // [m][k] chunks XOR-swizzled by (m&7)
    __shared__ short Bsm[128 * 64];   // [n][k] chunks XOR-swizzled by (n&7)

    const int tid  = threadIdx.x;
    const int wave = tid >> 6, lane = tid & 63;
    const int ln15 = lane & 15, quad = lane >> 4, ln7 = lane & 7;
    const int m0 = blockIdx.x * 128;
    const int n0 = blockIdx.y * 128;
    const int kt0 = blockIdx.z * 162;
    const int wm = (wave >> 1) * 64, wn = (wave & 1) * 64;

    // staging roles: thread stages 4 rows of A-tile and 4 rows of B-tile
    const int rbase = wave * 32 + (lane >> 3);      // + s*8
    const int cswz8 = ((lane & 7) ^ ((lane >> 3) & 7)) * 8;  // swizzled elem offs

    size_t aptr[4];  // pixel-base element offsets into h1
    size_t bptr[4];  // row-base element offsets into wt2t
#pragma unroll
    for (int s = 0; s < 4; ++s) {
        int r = rbase + s * 8;
        int m = m0 + r;
        int b = m / 36, sp = m % 36;
        int oh = sp / 6, ow = sp % 6;
        aptr[s] = (size_t)((b * 20 + 2 * oh) * 20 + 2 * ow) * 256 + cswz8;
        bptr[s] = (size_t)(n0 + r) * 20736 + cswz8;
    }
    short* alds = &Asm[(wave * 32) * 64 + lane * 8];  // + s*8*64
    short* blds = &Bsm[(wave * 32) * 64 + lane * 8];

    f32x4 acc[4][4];
#pragma unroll
    for (int i = 0; i < 4; ++i)
#pragma unroll
        for (int j = 0; j < 4; ++j) acc[i][j] = (f32x4)(0.f);

    for (int kt = kt0; kt < kt0 + 162; ++kt) {
        int q = kt >> 2;
        int kh = q / 9, kw = q - kh * 9;
        size_t aoff = (size_t)(kh * 20 + kw) * 256 + ((kt & 3) << 6);
        size_t boff = (size_t)kt << 6;
#pragma unroll
        for (int s = 0; s < 4; ++s)
            gld_lds16(h1 + aptr[s] + aoff, alds + s * 512);
#pragma unroll
        for (int s = 0; s < 4; ++s)
            gld_lds16(wt2t + bptr[s] + boff, blds + s * 512);
        __syncthreads();
#pragma unroll
        for (int ks = 0; ks < 2; ++ks) {
            bf16x8 af[4], bfr[4];
#pragma unroll
            for (int i = 0; i < 4; ++i) {
                int chunk = ((ks << 2) + quad) ^ ln7;
                af[i] = *(const bf16x8*)&Asm[(wm + i * 16 + ln15) * 64 + chunk * 8];
            }
#pragma unroll
            for (int j = 0; j < 4; ++j) {
                int chunk = ((ks << 2) + quad) ^ ln7;
                bfr[j] = *(const bf16x8*)&Bsm[(wn + j * 16 + ln15) * 64 + chunk * 8];
            }
#pragma unroll
            for (int i = 0; i < 4; ++i)
#pragma unroll
                for (int j = 0; j < 4; ++j)
                    acc[i][j] = __builtin_amdgcn_mfma_f32_16x16x32_bf16(
                        af[i], bfr[j], acc[i][j], 0, 0, 0);
        }
        __syncthreads();
    }

    // Epilogue: C[m][n] -> atomicAdd h2[b][oc][sp]; D layout col=lane&15,
    // row=(lane>>4)*4+reg  [m89-verified]
#pragma unroll
    for (int i = 0; i < 4; ++i) {
#pragma unroll
        for (int r = 0; r < 4; ++r) {
            int m = m0 + wm + i * 16 + quad * 4 + r;
            int b2 = m / 36, sp2 = m % 36;
            float* dst = h2 + (size_t)b2 * 9216 + sp2;
#pragma unroll
            for (int j = 0; j < 4; ++j) {
                int n = n0 + wn + j * 16 + ln15;
                atomicAdd(dst + n * 36, acc[i][j][r]);
            }
        }
    }
}

// ---------------------------------------------------------------------------
// Primary-capsule squash, in place on h2: groups of 8 consecutive floats.
__global__ void k_squash(float* __restrict__ h2) {
    int idx = blockIdx.x * 256 + threadIdx.x;          // 512*1152 capsules
    if (idx >= 512 * 1152) return;
    float* p = h2 + (size_t)idx * 8;
    float4 a = *(float4*)p, c = *(float4*)(p + 4);
    float n2 = a.x * a.x + a.y * a.y + a.z * a.z + a.w * a.w +
               c.x * c.x + c.y * c.y + c.z * c.z + c.w * c.w;
    float n = sqrtf(n2);
    float s = n2 / (1.f + n2) / (n + EPS);
    a.x *= s; a.y *= s; a.z *= s; a.w *= s;
    c.x *= s; c.y *= s; c.z *= s; c.w *= s;
    *(float4*)p = a;
    *(float4*)(p + 4) = c;
}

// ---------------------------------------------------------------------------
// Dynamic routing, one block per batch element. 320 threads = 10 o-caps x 32
// lanes. x_hat recomputed from caps_w (streamed 3x per block); b_logits in LDS.
__global__ __launch_bounds__(320) void k_routing(const float* __restrict__ u,
                                                 const float* __restrict__ cw,
                                                 float* __restrict__ out) {
    __shared__ float bl[10][1152];
    __shared__ float sv[10][16];
    __shared__ float stats_m[32], stats_si[32];
    __shared__ float scale_sh[10];
    const int t = threadIdx.x;
    const int b = blockIdx.x;
    const int o = t >> 5, lane = t & 31;
    const float* ub = u + (size_t)b * 9216;
    float v_loc[16];
#pragma unroll
    for (int d = 0; d < 16; ++d) v_loc[d] = 0.f;

    for (int pass = 0; pass < 3; ++pass) {
        float s_loc[16];
#pragma unroll
        for (int d = 0; d < 16; ++d) s_loc[d] = 0.f;
        if (pass > 0) {
#pragma unroll
            for (int d = 0; d < 16; ++d) v_loc[d] = sv[o][d];
        }
        for (int chunk = 0; chunk < 36; ++chunk) {
            int i = chunk * 32 + lane;
            float ui[8];
            *(float4*)ui       = *(const float4*)(ub + i * 8);
            *(float4*)(ui + 4) = *(const float4*)(ub + i * 8 + 4);
            const float4* wp = (const float4*)(cw + (size_t)(o * 1152 + i) * 128);
            float xh[16];
#pragma unroll
            for (int d = 0; d < 16; ++d) {
                float4 w0 = wp[d * 2], w1 = wp[d * 2 + 1];
                xh[d] = w0.x * ui[0] + w0.y * ui[1] + w0.z * ui[2] + w0.w * ui[3] +
                        w1.x * ui[4] + w1.y * ui[5] + w1.z * ui[6] + w1.w * ui[7];
            }
            float c;
            if (pass > 0) {
                float dot = 0.f;
#pragma unroll
                for (int d = 0; d < 16; ++d) dot += v_loc[d] * xh[d];
                float blv = (pass == 1) ? dot : (bl[o][i] + dot);
                bl[o][i] = blv;
                __syncthreads();
                if (t < 32) {
                    int i2 = chunk * 32 + t;
                    float mx = bl[0][i2];
#pragma unroll
                    for (int oo = 1; oo < 10; ++oo) mx = fmaxf(mx, bl[oo][i2]);
                    float se = 0.f;
#pragma unroll
                    for (int oo = 0; oo < 10; ++oo) se += expf(bl[oo][i2] - mx);
                    stats_m[t] = mx;
                    stats_si[t] = 1.f / se;
                }
                __syncthreads();
                c = expf(blv - stats_m[lane]) * stats_si[lane];
            } else {
                c = 0.1f;
            }
#pragma unroll
            for (int d = 0; d < 16; ++d) s_loc[d] += c * xh[d];
        }
#pragma unroll
        for (int off = 16; off > 0; off >>= 1) {
#pragma unroll
            for (int d = 0; d < 16; ++d) s_loc[d] += __shfl_down(s_loc[d], off, 32);
        }
        if (lane == 0) {
#pragma unroll
            for (int d = 0; d < 16; ++d) sv[o][d] = s_loc[d];
        }
        __syncthreads();
        if (pass < 2) {
            if (t < 10) {
                float n2 = 0.f;
#pragma unroll
                for (int d = 0; d < 16; ++d) n2 += sv[t][d] * sv[t][d];
                float n = sqrtf(n2);
                scale_sh[t] = n2 / (1.f + n2) / (n + EPS);
            }
            __syncthreads();
            if (t < 160) sv[t >> 4][t & 15] *= scale_sh[t >> 4];
            __syncthreads();
        } else {
            if (t < 10) {
                float n2 = 0.f;
#pragma unroll
                for (int d = 0; d < 16; ++d) n2 += sv[t][d] * sv[t][d];
                float n = sqrtf(n2);
                out[b * 10 + t] = (n2 / (1.f + n2)) * (n / (n + EPS));
            }
        }
    }
}

// ---------------------------------------------------------------------------
extern "C" void kernel_launch(void* const* d_in, const int* in_sizes, int n_in,
                              void* d_out, int out_size, void* d_ws, size_t ws_size,
                              hipStream_t stream) {
    const float* x  = (const float*)d_in[0];   // [512,1,28,28]
    const float* w1 = (const float*)d_in[1];   // [256,1,9,9]
    const float* b1 = (const float*)d_in[2];   // [256]
    const float* pw = (const float*)d_in[3];   // [256,256,9,9]
    const float* pb = (const float*)d_in[4];   // [256]
    const float* cw = (const float*)d_in[5];   // [10,1152,16,8]
    float* out = (float*)d_out;                // [512,10]

    char* ws = (char*)d_ws;
    unsigned short* h1   = (unsigned short*)ws;                    // 104,857,600 B
    float*          h2   = (float*)(ws + 104857600);               //  18,874,368 B
    float*          wt1  = (float*)(ws + 104857600 + 18874368);    //      82,944 B
    unsigned short* wt2t = (unsigned short*)(ws + 104857600 + 18874368 + 82944); // 10,616,832 B

    k_tw1<<<81, 256, 0, stream>>>(w1, wt1);
    k_tw2<<<20736, 256, 0, stream>>>(pw, wt2t);
    k_init_h2<<<18432, 256, 0, stream>>>(pb, h2);
    k_conv1<<<3200, 256, 0, stream>>>(x, wt1, b1, h1);
    k_conv2<<<dim3(144, 2, 2), 256, 0, stream>>>(h1, wt2t, h2);
    k_squash<<<2304, 256, 0, stream>>>(h2);
    k_routing<<<512, 320, 0, stream>>>(h2, cw, out);
}

// Round 3
// 1657.134 us; speedup vs baseline: 2.4114x; 1.0790x over previous
//
#include <hip/hip_runtime.h>
#include <hip/hip_bf16.h>
#include <hip/hip_fp16.h>
#include <math.h>

#define EPS 1e-8f

typedef __attribute__((ext_vector_type(8))) short bf16x8;
typedef __attribute__((ext_vector_type(4))) float f32x4;

__device__ static inline unsigned short f2bf(float f) {
    __hip_bfloat16 h = __float2bfloat16(f);
    return *reinterpret_cast<unsigned short*>(&h);
}

__device__ static inline void gld_lds16(const void* g, void* l) {
    __builtin_amdgcn_global_load_lds((const __attribute__((address_space(1))) void*)g,
                                     (__attribute__((address_space(3))) void*)l, 16, 0, 0);
}

// ---------------------------------------------------------------------------
// Transpose conv1 weights: wt1[k][n] = w1[n][k]; k in [0,81), n in [0,256)
__global__ void k_tw1(const float* __restrict__ w1, float* __restrict__ wt1) {
    int idx = blockIdx.x * 256 + threadIdx.x;
    if (idx >= 81 * 256) return;
    int k = idx >> 8, n = idx & 255;
    wt1[idx] = w1[n * 81 + k];
}

// conv2 weights -> bf16, layout wt2t[oc][k] with k = q*256+ic (q=kh*9+kw)
__global__ void k_tw2(const float* __restrict__ pw, unsigned short* __restrict__ wt2t) {
    int idx = blockIdx.x * 256 + threadIdx.x;          // 256*20736
    int oc = idx / 20736, k = idx % 20736;
    int q = k >> 8, ic = k & 255;
    wt2t[idx] = f2bf(pw[oc * 20736 + ic * 81 + q]);
}

// caps_w fp32 -> fp16 (same layout [o][i][d][k]); 2.95 MB -> L2-resident
__global__ void k_cwh(const float* __restrict__ cw, __half* __restrict__ cwh) {
    int idx = blockIdx.x * 256 + threadIdx.x;          // 1,474,560
    if (idx < 1474560) cwh[idx] = __float2half(cw[idx]);
}

// Initialize h2[b][c][sp] with conv2 bias[c] (split-K atomics accumulate on top)
__global__ void k_init_h2(const float* __restrict__ pb, float* __restrict__ h2) {
    int idx = blockIdx.x * 256 + threadIdx.x;          // 512*9216
    int c = (idx % 9216) / 36;
    h2[idx] = pb[c];
}

// ---------------------------------------------------------------------------
// conv1 as fp32 GEMM: M=512*400, N=256, K=81. Output h1 NHWC in bf16.
__global__ __launch_bounds__(256) void k_conv1(const float* __restrict__ x,
                                               const float* __restrict__ wt1,
                                               const float* __restrict__ b1,
                                               unsigned short* __restrict__ h1) {
    __shared__ float As[16][68];
    __shared__ float Bs[16][260];
    const int tid = threadIdx.x;
    const int m0 = blockIdx.x * 64;
    const int tr = tid >> 5, tc = tid & 31;
    float acc[8][8];
#pragma unroll
    for (int i = 0; i < 8; ++i)
#pragma unroll
        for (int j = 0; j < 8; ++j) acc[i][j] = 0.f;

    const int m_l = tid >> 2;
    const int k_lb = (tid & 3) * 4;
    const int m = m0 + m_l;
    const int b = m / 400, sp = m % 400;
    const int oh = sp / 20, ow = sp % 20;
    const float* xb = x + b * 784 + oh * 28 + ow;

    for (int k0 = 0; k0 < 81; k0 += 16) {
#pragma unroll
        for (int j = 0; j < 4; ++j) {
            int k = k0 + k_lb + j;
            float v = 0.f;
            if (k < 81) { int kh = k / 9, kw = k % 9; v = xb[kh * 28 + kw]; }
            As[k_lb + j][m_l] = v;
        }
        {
            int r = tid >> 4, cb = (tid & 15) * 16;
            int k = k0 + r;
            if (k < 81) {
                const float4* src = (const float4*)(wt1 + k * 256 + cb);
#pragma unroll
                for (int j = 0; j < 4; ++j) *(float4*)(&Bs[r][cb + j * 4]) = src[j];
            } else {
#pragma unroll
                for (int j = 0; j < 16; ++j) Bs[r][cb + j] = 0.f;
            }
        }
        __syncthreads();
#pragma unroll
        for (int kk = 0; kk < 16; ++kk) {
            float a[8], bb[8];
            *(float4*)a       = *(const float4*)(&As[kk][tr * 8]);
            *(float4*)(a + 4) = *(const float4*)(&As[kk][tr * 8 + 4]);
            *(float4*)bb       = *(const float4*)(&Bs[kk][tc * 8]);
            *(float4*)(bb + 4) = *(const float4*)(&Bs[kk][tc * 8 + 4]);
#pragma unroll
            for (int i = 0; i < 8; ++i)
#pragma unroll
                for (int j = 0; j < 8; ++j) acc[i][j] += a[i] * bb[j];
        }
        __syncthreads();
    }
    float bias[8];
    *(float4*)bias       = *(const float4*)(b1 + tc * 8);
    *(float4*)(bias + 4) = *(const float4*)(b1 + tc * 8 + 4);
#pragma unroll
    for (int i = 0; i < 8; ++i) {
        int mm = m0 + tr * 8 + i;
        unsigned short o16[8];
#pragma unroll
        for (int j = 0; j < 8; ++j) {
            float v = acc[i][j] + bias[j];
            o16[j] = f2bf(v > 0.f ? v : 0.f);
        }
        *(uint4*)(h1 + (size_t)mm * 256 + tc * 8) = *(uint4*)o16;
    }
}

// ---------------------------------------------------------------------------
// conv2 as bf16 MFMA GEMM: M=18432, N=256, K=20736. BM=128 BN=128 BK=64,
// split-K=2, global_load_lds w16 with XOR chunk swizzle.
__global__ __launch_bounds__(256) void k_conv2(const unsigned short* __restrict__ h1,
                                               const unsigned short* __restrict__ wt2t,
                                               float* __restrict__ h2) {
    __shared__ short Asm[128 * 64];
    __shared__ short Bsm[128 * 64];

    const int tid  = threadIdx.x;
    const int wave = tid >> 6, lane = tid & 63;
    const int ln15 = lane & 15, quad = lane >> 4, ln7 = lane & 7;
    const int m0 = blockIdx.x * 128;
    const int n0 = blockIdx.y * 128;
    const int kt0 = blockIdx.z * 162;
    const int wm = (wave >> 1) * 64, wn = (wave & 1) * 64;

    const int rbase = wave * 32 + (lane >> 3);
    const int cswz8 = ((lane & 7) ^ ((lane >> 3) & 7)) * 8;

    size_t aptr[4];
    size_t bptr[4];
#pragma unroll
    for (int s = 0; s < 4; ++s) {
        int r = rbase + s * 8;
        int m = m0 + r;
        int b = m / 36, sp = m % 36;
        int oh = sp / 6, ow = sp % 6;
        aptr[s] = (size_t)((b * 20 + 2 * oh) * 20 + 2 * ow) * 256 + cswz8;
        bptr[s] = (size_t)(n0 + r) * 20736 + cswz8;
    }
    short* alds = &Asm[(wave * 32) * 64 + lane * 8];
    short* blds = &Bsm[(wave * 32) * 64 + lane * 8];

    f32x4 acc[4][4];
#pragma unroll
    for (int i = 0; i < 4; ++i)
#pragma unroll
        for (int j = 0; j < 4; ++j) acc[i][j] = (f32x4)(0.f);

    for (int kt = kt0; kt < kt0 + 162; ++kt) {
        int q = kt >> 2;
        int kh = q / 9, kw = q - kh * 9;
        size_t aoff = (size_t)(kh * 20 + kw) * 256 + ((kt & 3) << 6);
        size_t boff = (size_t)kt << 6;
#pragma unroll
        for (int s = 0; s < 4; ++s)
            gld_lds16(h1 + aptr[s] + aoff, alds + s * 512);
#pragma unroll
        for (int s = 0; s < 4; ++s)
            gld_lds16(wt2t + bptr[s] + boff, blds + s * 512);
        __syncthreads();
#pragma unroll
        for (int ks = 0; ks < 2; ++ks) {
            bf16x8 af[4], bfr[4];
#pragma unroll
            for (int i = 0; i < 4; ++i) {
                int chunk = ((ks << 2) + quad) ^ ln7;
                af[i] = *(const bf16x8*)&Asm[(wm + i * 16 + ln15) * 64 + chunk * 8];
            }
#pragma unroll
            for (int j = 0; j < 4; ++j) {
                int chunk = ((ks << 2) + quad) ^ ln7;
                bfr[j] = *(const bf16x8*)&Bsm[(wn + j * 16 + ln15) * 64 + chunk * 8];
            }
#pragma unroll
            for (int i = 0; i < 4; ++i)
#pragma unroll
                for (int j = 0; j < 4; ++j)
                    acc[i][j] = __builtin_amdgcn_mfma_f32_16x16x32_bf16(
                        af[i], bfr[j], acc[i][j], 0, 0, 0);
        }
        __syncthreads();
    }

#pragma unroll
    for (int i = 0; i < 4; ++i) {
#pragma unroll
        for (int r = 0; r < 4; ++r) {
            int m = m0 + wm + i * 16 + quad * 4 + r;
            int b2 = m / 36, sp2 = m % 36;
            float* dst = h2 + (size_t)b2 * 9216 + sp2;
#pragma unroll
            for (int j = 0; j < 4; ++j) {
                int n = n0 + wn + j * 16 + ln15;
                atomicAdd(dst + n * 36, acc[i][j][r]);
            }
        }
    }
}

// ---------------------------------------------------------------------------
// Primary-capsule squash, in place on h2.
__global__ void k_squash(float* __restrict__ h2) {
    int idx = blockIdx.x * 256 + threadIdx.x;
    if (idx >= 512 * 1152) return;
    float* p = h2 + (size_t)idx * 8;
    float4 a = *(float4*)p, c = *(float4*)(p + 4);
    float n2 = a.x * a.x + a.y * a.y + a.z * a.z + a.w * a.w +
               c.x * c.x + c.y * c.y + c.z * c.z + c.w * c.w;
    float n = sqrtf(n2);
    float s = n2 / (1.f + n2) / (n + EPS);
    a.x *= s; a.y *= s; a.z *= s; a.w *= s;
    c.x *= s; c.y *= s; c.z *= s; c.w *= s;
    *(float4*)p = a;
    *(float4*)(p + 4) = c;
}

// ---------------------------------------------------------------------------
// Dynamic routing v2. One block per b, 640 threads = 10 o-caps x 64 lanes.
// Key identity: b_logits after p passes = (v_1+...+v_p) . x_hat, so only
// vsum[10][16] persists; dots recomputed per pass. Phases per pass:
//   P1: dots[o][i] = vsum[o].xh(o,i)            (barrier-free sweep)
//   P2: softmax over o per i, dots <- c          (thread-local, 10-wide)
//   P3: s[o] = sum_i c*xh, shfl-reduce, squash   (barrier-free sweep)
// caps_w in fp16 (2.95 MB, per-XCD-L2-resident).
__global__ __launch_bounds__(640) void k_routing(const float* __restrict__ u,
                                                 const __half* __restrict__ cwh,
                                                 float* __restrict__ out) {
    __shared__ float dots[10][1152];   // 46080 B, per-pass scratch
    __shared__ float sv[10][16];
    __shared__ float vsum[10][16];
    __shared__ float scale_sh[10];
    const int t = threadIdx.x;
    const int b = blockIdx.x;
    const int o = t >> 6, lane = t & 63;
    const float* ub = u + (size_t)b * 9216;

    if (t < 160) vsum[t >> 4][t & 15] = 0.f;
    __syncthreads();

    for (int pass = 0; pass < 3; ++pass) {
        if (pass > 0) {
            // ---- Phase 1: dots[o][i] = vsum[o] . xh
            float vs[16];
#pragma unroll
            for (int d = 0; d < 16; ++d) vs[d] = vsum[o][d];
            for (int chunk = 0; chunk < 18; ++chunk) {
                int i = chunk * 64 + lane;
                float ui[8];
                *(float4*)ui       = *(const float4*)(ub + i * 8);
                *(float4*)(ui + 4) = *(const float4*)(ub + i * 8 + 4);
                const uint4* wp = (const uint4*)(cwh + ((size_t)(o * 1152 + i) << 7));
                float dot = 0.f;
#pragma unroll
                for (int d = 0; d < 16; ++d) {
                    uint4 w = wp[d];
                    float2 f0 = __half22float2(*(__half2*)&w.x);
                    float2 f1 = __half22float2(*(__half2*)&w.y);
                    float2 f2 = __half22float2(*(__half2*)&w.z);
                    float2 f3 = __half22float2(*(__half2*)&w.w);
                    float xh = f0.x * ui[0] + f0.y * ui[1] + f1.x * ui[2] + f1.y * ui[3]
                             + f2.x * ui[4] + f2.y * ui[5] + f3.x * ui[6] + f3.y * ui[7];
                    dot += vs[d] * xh;
                }
                dots[o][i] = dot;
            }
            __syncthreads();
            // ---- Phase 2: per-i softmax over o; overwrite dots with c
            for (int i = t; i < 1152; i += 640) {
                float dv[10];
#pragma unroll
                for (int oo = 0; oo < 10; ++oo) dv[oo] = dots[oo][i];
                float mx = dv[0];
#pragma unroll
                for (int oo = 1; oo < 10; ++oo) mx = fmaxf(mx, dv[oo]);
                float se = 0.f;
#pragma unroll
                for (int oo = 0; oo < 10; ++oo) { dv[oo] = expf(dv[oo] - mx); se += dv[oo]; }
                float si = 1.f / se;
#pragma unroll
                for (int oo = 0; oo < 10; ++oo) dots[oo][i] = dv[oo] * si;
            }
            __syncthreads();
        }
        // ---- Phase 3: s[o] = sum_i c * xh
        float s_loc[16];
#pragma unroll
        for (int d = 0; d < 16; ++d) s_loc[d] = 0.f;
        for (int chunk = 0; chunk < 18; ++chunk) {
            int i = chunk * 64 + lane;
            float ui[8];
            *(float4*)ui       = *(const float4*)(ub + i * 8);
            *(float4*)(ui + 4) = *(const float4*)(ub + i * 8 + 4);
            float c = (pass == 0) ? 0.1f : dots[o][i];
            const uint4* wp = (const uint4*)(cwh + ((size_t)(o * 1152 + i) << 7));
#pragma unroll
            for (int d = 0; d < 16; ++d) {
                uint4 w = wp[d];
                float2 f0 = __half22float2(*(__half2*)&w.x);
                float2 f1 = __half22float2(*(__half2*)&w.y);
                float2 f2 = __half22float2(*(__half2*)&w.z);
                float2 f3 = __half22float2(*(__half2*)&w.w);
                float xh = f0.x * ui[0] + f0.y * ui[1] + f1.x * ui[2] + f1.y * ui[3]
                         + f2.x * ui[4] + f2.y * ui[5] + f3.x * ui[6] + f3.y * ui[7];
                s_loc[d] += c * xh;
            }
        }
#pragma unroll
        for (int off = 32; off > 0; off >>= 1)
#pragma unroll
            for (int d = 0; d < 16; ++d) s_loc[d] += __shfl_down(s_loc[d], off, 64);
        if (lane == 0) {
#pragma unroll
            for (int d = 0; d < 16; ++d) sv[o][d] = s_loc[d];
        }
        __syncthreads();
        if (pass < 2) {
            if (t < 10) {
                float n2 = 0.f;
#pragma unroll
                for (int d = 0; d < 16; ++d) n2 += sv[t][d] * sv[t][d];
                float n = sqrtf(n2);
                scale_sh[t] = n2 / (1.f + n2) / (n + EPS);
            }
            __syncthreads();
            if (t < 160) {
                int oo = t >> 4, d = t & 15;
                vsum[oo][d] += sv[oo][d] * scale_sh[oo];
            }
            __syncthreads();
        } else {
            if (t < 10) {
                float n2 = 0.f;
#pragma unroll
                for (int d = 0; d < 16; ++d) n2 += sv[t][d] * sv[t][d];
                float n = sqrtf(n2);
                out[b * 10 + t] = (n2 / (1.f + n2)) * (n / (n + EPS));
            }
        }
    }
}

// ---------------------------------------------------------------------------
extern "C" void kernel_launch(void* const* d_in, const int* in_sizes, int n_in,
                              void* d_out, int out_size, void* d_ws, size_t ws_size,
                              hipStream_t stream) {
    const float* x  = (const float*)d_in[0];   // [512,1,28,28]
    const float* w1 = (const float*)d_in[1];   // [256,1,9,9]
    const float* b1 = (const float*)d_in[2];   // [256]
    const float* pw = (const float*)d_in[3];   // [256,256,9,9]
    const float* pb = (const float*)d_in[4];   // [256]
    const float* cw = (const float*)d_in[5];   // [10,1152,16,8]
    float* out = (float*)d_out;                // [512,10]

    char* ws = (char*)d_ws;
    unsigned short* h1   = (unsigned short*)ws;                       // 104,857,600 B
    float*          h2   = (float*)(ws + 104857600);                  //  18,874,368 B
    float*          wt1  = (float*)(ws + 104857600 + 18874368);       //      82,944 B
    unsigned short* wt2t = (unsigned short*)(ws + 123815312 - 82944 + 82944); // keep layout below
    wt2t = (unsigned short*)(ws + 104857600 + 18874368 + 82944);      //  10,616,832 B
    __half*         cwh  = (__half*)(ws + 104857600 + 18874368 + 82944 + 10616832); // 2,949,120 B

    k_tw1<<<81, 256, 0, stream>>>(w1, wt1);
    k_tw2<<<20736, 256, 0, stream>>>(pw, wt2t);
    k_cwh<<<5760, 256, 0, stream>>>(cw, cwh);
    k_init_h2<<<18432, 256, 0, stream>>>(pb, h2);
    k_conv1<<<3200, 256, 0, stream>>>(x, wt1, b1, h1);
    k_conv2<<<dim3(144, 2, 2), 256, 0, stream>>>(h1, wt2t, h2);
    k_squash<<<2304, 256, 0, stream>>>(h2);
    k_routing<<<512, 640, 0, stream>>>(h2, cwh, out);
}

// Round 4
// 1061.440 us; speedup vs baseline: 3.7646x; 1.5612x over previous
//
#include <hip/hip_runtime.h>
#include <hip/hip_bf16.h>
#include <hip/hip_fp16.h>
#include <math.h>

#define EPS 1e-8f

typedef __attribute__((ext_vector_type(8))) short bf16x8;
typedef __attribute__((ext_vector_type(4))) float f32x4;

__device__ static inline unsigned short f2bf(float f) {
    __hip_bfloat16 h = __float2bfloat16(f);
    return *reinterpret_cast<unsigned short*>(&h);
}

__device__ static inline void gld_lds16(const void* g, void* l) {
    __builtin_amdgcn_global_load_lds((const __attribute__((address_space(1))) void*)g,
                                     (__attribute__((address_space(3))) void*)l, 16, 0, 0);
}

__device__ static inline void h8tof(uint4 w, float* f) {
    float2 a = __half22float2(*(__half2*)&w.x);
    float2 b = __half22float2(*(__half2*)&w.y);
    float2 c = __half22float2(*(__half2*)&w.z);
    float2 d = __half22float2(*(__half2*)&w.w);
    f[0] = a.x; f[1] = a.y; f[2] = b.x; f[3] = b.y;
    f[4] = c.x; f[5] = c.y; f[6] = d.x; f[7] = d.y;
}

// ---------------------------------------------------------------------------
// Transpose conv1 weights: wt1[k][n] = w1[n][k]
__global__ void k_tw1(const float* __restrict__ w1, float* __restrict__ wt1) {
    int idx = blockIdx.x * 256 + threadIdx.x;
    if (idx >= 81 * 256) return;
    int k = idx >> 8, n = idx & 255;
    wt1[idx] = w1[n * 81 + k];
}

// conv2 weights -> bf16, layout wt2t[oc][k] with k = q*256+ic
__global__ void k_tw2(const float* __restrict__ pw, unsigned short* __restrict__ wt2t) {
    int idx = blockIdx.x * 256 + threadIdx.x;          // 256*20736
    int oc = idx / 20736, k = idx % 20736;
    int q = k >> 8, ic = k & 255;
    wt2t[idx] = f2bf(pw[oc * 20736 + ic * 81 + q]);
}

// caps_w fp32 -> fp16 (layout [o][i][d][k]); 2.95 MB
__global__ void k_cwh(const float* __restrict__ cw, __half* __restrict__ cwh) {
    int idx = blockIdx.x * 256 + threadIdx.x;
    if (idx < 1474560) cwh[idx] = __float2half(cw[idx]);
}

// Initialize h2[b][c][sp] with conv2 bias[c]
__global__ void k_init_h2(const float* __restrict__ pb, float* __restrict__ h2) {
    int idx = blockIdx.x * 256 + threadIdx.x;
    int c = (idx % 9216) / 36;
    h2[idx] = pb[c];
}

// ---------------------------------------------------------------------------
// conv1 as fp32 GEMM: M=512*400, N=256, K=81. Output h1 NHWC in bf16.
__global__ __launch_bounds__(256) void k_conv1(const float* __restrict__ x,
                                               const float* __restrict__ wt1,
                                               const float* __restrict__ b1,
                                               unsigned short* __restrict__ h1) {
    __shared__ float As[16][68];
    __shared__ float Bs[16][260];
    const int tid = threadIdx.x;
    const int m0 = blockIdx.x * 64;
    const int tr = tid >> 5, tc = tid & 31;
    float acc[8][8];
#pragma unroll
    for (int i = 0; i < 8; ++i)
#pragma unroll
        for (int j = 0; j < 8; ++j) acc[i][j] = 0.f;

    const int m_l = tid >> 2;
    const int k_lb = (tid & 3) * 4;
    const int m = m0 + m_l;
    const int b = m / 400, sp = m % 400;
    const int oh = sp / 20, ow = sp % 20;
    const float* xb = x + b * 784 + oh * 28 + ow;

    for (int k0 = 0; k0 < 81; k0 += 16) {
#pragma unroll
        for (int j = 0; j < 4; ++j) {
            int k = k0 + k_lb + j;
            float v = 0.f;
            if (k < 81) { int kh = k / 9, kw = k % 9; v = xb[kh * 28 + kw]; }
            As[k_lb + j][m_l] = v;
        }
        {
            int r = tid >> 4, cb = (tid & 15) * 16;
            int k = k0 + r;
            if (k < 81) {
                const float4* src = (const float4*)(wt1 + k * 256 + cb);
#pragma unroll
                for (int j = 0; j < 4; ++j) *(float4*)(&Bs[r][cb + j * 4]) = src[j];
            } else {
#pragma unroll
                for (int j = 0; j < 16; ++j) Bs[r][cb + j] = 0.f;
            }
        }
        __syncthreads();
#pragma unroll
        for (int kk = 0; kk < 16; ++kk) {
            float a[8], bb[8];
            *(float4*)a       = *(const float4*)(&As[kk][tr * 8]);
            *(float4*)(a + 4) = *(const float4*)(&As[kk][tr * 8 + 4]);
            *(float4*)bb       = *(const float4*)(&Bs[kk][tc * 8]);
            *(float4*)(bb + 4) = *(const float4*)(&Bs[kk][tc * 8 + 4]);
#pragma unroll
            for (int i = 0; i < 8; ++i)
#pragma unroll
                for (int j = 0; j < 8; ++j) acc[i][j] += a[i] * bb[j];
        }
        __syncthreads();
    }
    float bias[8];
    *(float4*)bias       = *(const float4*)(b1 + tc * 8);
    *(float4*)(bias + 4) = *(const float4*)(b1 + tc * 8 + 4);
#pragma unroll
    for (int i = 0; i < 8; ++i) {
        int mm = m0 + tr * 8 + i;
        unsigned short o16[8];
#pragma unroll
        for (int j = 0; j < 8; ++j) {
            float v = acc[i][j] + bias[j];
            o16[j] = f2bf(v > 0.f ? v : 0.f);
        }
        *(uint4*)(h1 + (size_t)mm * 256 + tc * 8) = *(uint4*)o16;
    }
}

// ---------------------------------------------------------------------------
// conv2 as bf16 MFMA GEMM: BM=128 BN=128 BK=64, split-K=2, gld_lds w16 + XOR swizzle
__global__ __launch_bounds__(256) void k_conv2(const unsigned short* __restrict__ h1,
                                               const unsigned short* __restrict__ wt2t,
                                               float* __restrict__ h2) {
    __shared__ short Asm[128 * 64];
    __shared__ short Bsm[128 * 64];

    const int tid  = threadIdx.x;
    const int wave = tid >> 6, lane = tid & 63;
    const int ln15 = lane & 15, quad = lane >> 4, ln7 = lane & 7;
    const int m0 = blockIdx.x * 128;
    const int n0 = blockIdx.y * 128;
    const int kt0 = blockIdx.z * 162;
    const int wm = (wave >> 1) * 64, wn = (wave & 1) * 64;

    const int rbase = wave * 32 + (lane >> 3);
    const int cswz8 = ((lane & 7) ^ ((lane >> 3) & 7)) * 8;

    size_t aptr[4];
    size_t bptr[4];
#pragma unroll
    for (int s = 0; s < 4; ++s) {
        int r = rbase + s * 8;
        int m = m0 + r;
        int b = m / 36, sp = m % 36;
        int oh = sp / 6, ow = sp % 6;
        aptr[s] = (size_t)((b * 20 + 2 * oh) * 20 + 2 * ow) * 256 + cswz8;
        bptr[s] = (size_t)(n0 + r) * 20736 + cswz8;
    }
    short* alds = &Asm[(wave * 32) * 64 + lane * 8];
    short* blds = &Bsm[(wave * 32) * 64 + lane * 8];

    f32x4 acc[4][4];
#pragma unroll
    for (int i = 0; i < 4; ++i)
#pragma unroll
        for (int j = 0; j < 4; ++j) acc[i][j] = (f32x4)(0.f);

    for (int kt = kt0; kt < kt0 + 162; ++kt) {
        int q = kt >> 2;
        int kh = q / 9, kw = q - kh * 9;
        size_t aoff = (size_t)(kh * 20 + kw) * 256 + ((kt & 3) << 6);
        size_t boff = (size_t)kt << 6;
#pragma unroll
        for (int s = 0; s < 4; ++s)
            gld_lds16(h1 + aptr[s] + aoff, alds + s * 512);
#pragma unroll
        for (int s = 0; s < 4; ++s)
            gld_lds16(wt2t + bptr[s] + boff, blds + s * 512);
        __syncthreads();
#pragma unroll
        for (int ks = 0; ks < 2; ++ks) {
            bf16x8 af[4], bfr[4];
#pragma unroll
            for (int i = 0; i < 4; ++i) {
                int chunk = ((ks << 2) + quad) ^ ln7;
                af[i] = *(const bf16x8*)&Asm[(wm + i * 16 + ln15) * 64 + chunk * 8];
            }
#pragma unroll
            for (int j = 0; j < 4; ++j) {
                int chunk = ((ks << 2) + quad) ^ ln7;
                bfr[j] = *(const bf16x8*)&Bsm[(wn + j * 16 + ln15) * 64 + chunk * 8];
            }
#pragma unroll
            for (int i = 0; i < 4; ++i)
#pragma unroll
                for (int j = 0; j < 4; ++j)
                    acc[i][j] = __builtin_amdgcn_mfma_f32_16x16x32_bf16(
                        af[i], bfr[j], acc[i][j], 0, 0, 0);
        }
        __syncthreads();
    }

#pragma unroll
    for (int i = 0; i < 4; ++i) {
#pragma unroll
        for (int r = 0; r < 4; ++r) {
            int m = m0 + wm + i * 16 + quad * 4 + r;
            int b2 = m / 36, sp2 = m % 36;
            float* dst = h2 + (size_t)b2 * 9216 + sp2;
#pragma unroll
            for (int j = 0; j < 4; ++j) {
                int n = n0 + wn + j * 16 + ln15;
                atomicAdd(dst + n * 36, acc[i][j][r]);
            }
        }
    }
}

// ---------------------------------------------------------------------------
// Primary-capsule squash, in place on h2.
__global__ void k_squash(float* __restrict__ h2) {
    int idx = blockIdx.x * 256 + threadIdx.x;
    if (idx >= 512 * 1152) return;
    float* p = h2 + (size_t)idx * 8;
    float4 a = *(float4*)p, c = *(float4*)(p + 4);
    float n2 = a.x * a.x + a.y * a.y + a.z * a.z + a.w * a.w +
               c.x * c.x + c.y * c.y + c.z * c.z + c.w * c.w;
    float n = sqrtf(n2);
    float s = n2 / (1.f + n2) / (n + EPS);
    a.x *= s; a.y *= s; a.z *= s; a.w *= s;
    c.x *= s; c.y *= s; c.z *= s; c.w *= s;
    *(float4*)p = a;
    *(float4*)(p + 4) = c;
}

// ---------------------------------------------------------------------------
// Materialize x_hat[b][o][i][d] in fp16 + s0[b][o][d] = sum_i xh (fp32).
// grid (512, 10), 256 threads.
__global__ __launch_bounds__(256) void k_xhat(const float* __restrict__ u,
                                              const __half* __restrict__ cwh,
                                              __half* __restrict__ xhat,
                                              float* __restrict__ s0) {
    __shared__ float part[4][16];
    const int b = blockIdx.x, o = blockIdx.y;
    const int t = threadIdx.x;
    const float* ub = u + (size_t)b * 9216;
    __half* xob = xhat + ((size_t)(b * 10 + o) * 1152) * 16;
    float s_loc[16];
#pragma unroll
    for (int d = 0; d < 16; ++d) s_loc[d] = 0.f;

    for (int i = t; i < 1152; i += 256) {
        float ui[8];
        *(float4*)ui       = *(const float4*)(ub + i * 8);
        *(float4*)(ui + 4) = *(const float4*)(ub + i * 8 + 4);
        const uint4* wp = (const uint4*)(cwh + ((size_t)(o * 1152 + i) << 7));
        __half xh16[16];
#pragma unroll
        for (int d = 0; d < 16; ++d) {
            float f[8];
            h8tof(wp[d], f);
            float xh = f[0] * ui[0] + f[1] * ui[1] + f[2] * ui[2] + f[3] * ui[3]
                     + f[4] * ui[4] + f[5] * ui[5] + f[6] * ui[6] + f[7] * ui[7];
            s_loc[d] += xh;
            xh16[d] = __float2half(xh);
        }
        __half* dst = xob + (size_t)i * 16;
        *(uint4*)dst       = *(uint4*)xh16;
        *(uint4*)(dst + 8) = *(uint4*)(xh16 + 8);
    }
    // reduce s_loc over 256 threads
#pragma unroll
    for (int off = 32; off > 0; off >>= 1)
#pragma unroll
        for (int d = 0; d < 16; ++d) s_loc[d] += __shfl_down(s_loc[d], off, 64);
    if ((t & 63) == 0) {
#pragma unroll
        for (int d = 0; d < 16; ++d) part[t >> 6][d] = s_loc[d];
    }
    __syncthreads();
    if (t < 16)
        s0[(b * 10 + o) * 16 + t] = part[0][t] + part[1][t] + part[2][t] + part[3][t];
}

// ---------------------------------------------------------------------------
// Dynamic routing v3: reads materialized fp16 x_hat. One block per b,
// 640 threads = 10 o x 64 lanes. Pass0 free via s0. Per pass ONE sweep:
// per 192-i group: dots -> barrier -> softmax in LDS -> barrier -> accumulate
// (xh kept in registers across the barriers). b_logits identity:
// bl after p passes = (v1+..+vp) . xh, so only vsum[10][16] persists.
__global__ __launch_bounds__(640) void k_routing(const __half* __restrict__ xhat,
                                                 const float* __restrict__ s0,
                                                 float* __restrict__ out) {
    __shared__ float dots[10][1152];
    __shared__ float sv[10][16];
    __shared__ float vsum[10][16];
    __shared__ float scale_sh[10];
    const int t = threadIdx.x;
    const int b = blockIdx.x;
    const int o = t >> 6, lane = t & 63;
    const __half* xb = xhat + ((size_t)(b * 10 + o) * 1152) * 16;

    // pass 0: v1 = squash(0.1 * s0[b][o])
    if (t < 160) {
        int oo = t >> 4, d = t & 15;
        sv[oo][d] = 0.1f * s0[(b * 10 + oo) * 16 + d];
    }
    __syncthreads();
    if (t < 10) {
        float n2 = 0.f;
#pragma unroll
        for (int d = 0; d < 16; ++d) n2 += sv[t][d] * sv[t][d];
        float n = sqrtf(n2);
        scale_sh[t] = n2 / (1.f + n2) / (n + EPS);
    }
    __syncthreads();
    if (t < 160) vsum[t >> 4][t & 15] = sv[t >> 4][t & 15] * scale_sh[t >> 4];
    __syncthreads();

    for (int pass = 1; pass <= 2; ++pass) {
        float vs[16];
#pragma unroll
        for (int d = 0; d < 16; ++d) vs[d] = vsum[o][d];
        float s_loc[16];
#pragma unroll
        for (int d = 0; d < 16; ++d) s_loc[d] = 0.f;

        for (int g = 0; g < 6; ++g) {
            uint4 xq[3][2];
#pragma unroll
            for (int j = 0; j < 3; ++j) {
                int i = g * 192 + j * 64 + lane;
                const uint4* p = (const uint4*)(xb + (size_t)i * 16);
                xq[j][0] = p[0];
                xq[j][1] = p[1];
                float f0[8], f1[8];
                h8tof(xq[j][0], f0);
                h8tof(xq[j][1], f1);
                float dd = 0.f;
#pragma unroll
                for (int d = 0; d < 8; ++d) dd += vs[d] * f0[d] + vs[d + 8] * f1[d];
                dots[o][i] = dd;
            }
            __syncthreads();
            if (t < 192) {
                int i = g * 192 + t;
                float dv[10];
#pragma unroll
                for (int oo = 0; oo < 10; ++oo) dv[oo] = dots[oo][i];
                float mx = dv[0];
#pragma unroll
                for (int oo = 1; oo < 10; ++oo) mx = fmaxf(mx, dv[oo]);
                float se = 0.f;
#pragma unroll
                for (int oo = 0; oo < 10; ++oo) { dv[oo] = __expf(dv[oo] - mx); se += dv[oo]; }
                float si = 1.f / se;
#pragma unroll
                for (int oo = 0; oo < 10; ++oo) dots[oo][i] = dv[oo] * si;
            }
            __syncthreads();
#pragma unroll
            for (int j = 0; j < 3; ++j) {
                int i = g * 192 + j * 64 + lane;
                float c = dots[o][i];
                float f0[8], f1[8];
                h8tof(xq[j][0], f0);
                h8tof(xq[j][1], f1);
#pragma unroll
                for (int d = 0; d < 8; ++d) {
                    s_loc[d]     += c * f0[d];
                    s_loc[d + 8] += c * f1[d];
                }
            }
        }
#pragma unroll
        for (int off = 32; off > 0; off >>= 1)
#pragma unroll
            for (int d = 0; d < 16; ++d) s_loc[d] += __shfl_down(s_loc[d], off, 64);
        if (lane == 0) {
#pragma unroll
            for (int d = 0; d < 16; ++d) sv[o][d] = s_loc[d];
        }
        __syncthreads();
        if (pass == 1) {
            if (t < 10) {
                float n2 = 0.f;
#pragma unroll
                for (int d = 0; d < 16; ++d) n2 += sv[t][d] * sv[t][d];
                float n = sqrtf(n2);
                scale_sh[t] = n2 / (1.f + n2) / (n + EPS);
            }
            __syncthreads();
            if (t < 160) {
                int oo = t >> 4, d = t & 15;
                vsum[oo][d] += sv[oo][d] * scale_sh[oo];
            }
            __syncthreads();
        } else {
            if (t < 10) {
                float n2 = 0.f;
#pragma unroll
                for (int d = 0; d < 16; ++d) n2 += sv[t][d] * sv[t][d];
                float n = sqrtf(n2);
                out[b * 10 + t] = (n2 / (1.f + n2)) * (n / (n + EPS));
            }
        }
    }
}

// ---------------------------------------------------------------------------
extern "C" void kernel_launch(void* const* d_in, const int* in_sizes, int n_in,
                              void* d_out, int out_size, void* d_ws, size_t ws_size,
                              hipStream_t stream) {
    const float* x  = (const float*)d_in[0];   // [512,1,28,28]
    const float* w1 = (const float*)d_in[1];   // [256,1,9,9]
    const float* b1 = (const float*)d_in[2];   // [256]
    const float* pw = (const float*)d_in[3];   // [256,256,9,9]
    const float* pb = (const float*)d_in[4];   // [256]
    const float* cw = (const float*)d_in[5];   // [10,1152,16,8]
    float* out = (float*)d_out;                // [512,10]

    char* ws = (char*)d_ws;
    // xhat (fp16, 188,743,680 B) aliases h1 (104,857,600 B) + wt2t
    // (10,616,832 B) -- both dead before k_xhat runs.
    __half*         xhat = (__half*)ws;
    unsigned short* h1   = (unsigned short*)ws;
    unsigned short* wt2t = (unsigned short*)(ws + 104857600);
    float*          h2   = (float*)(ws + 188743680);            // 18,874,368 B
    float*          wt1  = (float*)(ws + 207618048);            //     82,944 B
    __half*         cwh  = (__half*)(ws + 207700992);           //  2,949,120 B
    float*          s0   = (float*)(ws + 210650112);            //    327,680 B
    // total 210,977,792 B

    k_tw1<<<81, 256, 0, stream>>>(w1, wt1);
    k_tw2<<<20736, 256, 0, stream>>>(pw, wt2t);
    k_cwh<<<5760, 256, 0, stream>>>(cw, cwh);
    k_init_h2<<<18432, 256, 0, stream>>>(pb, h2);
    k_conv1<<<3200, 256, 0, stream>>>(x, wt1, b1, h1);
    k_conv2<<<dim3(144, 2, 2), 256, 0, stream>>>(h1, wt2t, h2);
    k_squash<<<2304, 256, 0, stream>>>(h2);
    k_xhat<<<dim3(512, 10), 256, 0, stream>>>(h2, cwh, xhat, s0);
    k_routing<<<512, 640, 0, stream>>>(xhat, s0, out);
}

// Round 5
// 716.086 us; speedup vs baseline: 5.5803x; 1.4823x over previous
//
#include <hip/hip_runtime.h>
#include <hip/hip_bf16.h>
#include <hip/hip_fp16.h>
#include <math.h>

#define EPS 1e-8f

typedef __attribute__((ext_vector_type(8))) short bf16x8;
typedef __attribute__((ext_vector_type(8))) _Float16 f16x8;
typedef __attribute__((ext_vector_type(4))) float f32x4;

__device__ static inline unsigned short f2bf(float f) {
    __hip_bfloat16 h = __float2bfloat16(f);
    return *reinterpret_cast<unsigned short*>(&h);
}
__device__ static inline unsigned short f2h(float f) {
    __half h = __float2half(f);
    return *reinterpret_cast<unsigned short*>(&h);
}

__device__ static inline void gld_lds16(const void* g, void* l) {
    __builtin_amdgcn_global_load_lds((const __attribute__((address_space(1))) void*)g,
                                     (__attribute__((address_space(3))) void*)l, 16, 0, 0);
}

__device__ static inline void h8tof(uint4 w, float* f) {
    float2 a = __half22float2(*(__half2*)&w.x);
    float2 b = __half22float2(*(__half2*)&w.y);
    float2 c = __half22float2(*(__half2*)&w.z);
    float2 d = __half22float2(*(__half2*)&w.w);
    f[0] = a.x; f[1] = a.y; f[2] = b.x; f[3] = b.y;
    f[4] = c.x; f[5] = c.y; f[6] = d.x; f[7] = d.y;
}

// ---------------------------------------------------------------------------
// x fp32 -> fp16
__global__ void k_cast_x(const float* __restrict__ x, unsigned short* __restrict__ xh) {
    int idx = blockIdx.x * 256 + threadIdx.x;          // 512*784 = 401408
    if (idx < 401408) xh[idx] = f2h(x[idx]);
}

// conv1 weights -> fp16 [n][96], k zero-padded 81->96
__global__ void k_tw1h(const float* __restrict__ w1, unsigned short* __restrict__ wt1h) {
    int idx = blockIdx.x * 256 + threadIdx.x;          // 256*96 = 24576
    if (idx >= 24576) return;
    int n = idx / 96, k = idx % 96;
    wt1h[idx] = (k < 81) ? f2h(w1[n * 81 + k]) : (unsigned short)0;
}

// conv2 weights -> bf16, layout wt2t[oc][k] with k = q*256+ic
__global__ void k_tw2(const float* __restrict__ pw, unsigned short* __restrict__ wt2t) {
    int idx = blockIdx.x * 256 + threadIdx.x;          // 256*20736
    int oc = idx / 20736, k = idx % 20736;
    int q = k >> 8, ic = k & 255;
    wt2t[idx] = f2bf(pw[oc * 20736 + ic * 81 + q]);
}

// caps_w fp32 -> fp16 (layout [o][i][d][k]); 2.95 MB
__global__ void k_cwh(const float* __restrict__ cw, __half* __restrict__ cwh) {
    int idx = blockIdx.x * 256 + threadIdx.x;
    if (idx < 1474560) cwh[idx] = __float2half(cw[idx]);
}

// ---------------------------------------------------------------------------
// conv1 as fp16 MFMA GEMM: M=204800 (b*400+oh*20+ow), N=256, K=81 pad 96.
// BM=128 BN=128, single K stage, 4 waves each 64x64 (4x4 mfma 16x16x32 f16).
// Output h1[m][n] bf16 (NHWC).
__global__ __launch_bounds__(256) void k_conv1(const unsigned short* __restrict__ xh,
                                               const unsigned short* __restrict__ wt1h,
                                               const float* __restrict__ b1,
                                               unsigned short* __restrict__ h1) {
    __shared__ unsigned short Asm[128 * 104];   // pitch 104 (208 B): 2-way-free b128
    __shared__ unsigned short Bsm[128 * 104];
    const int tid = threadIdx.x;
    const int wave = tid >> 6, lane = tid & 63;
    const int ln15 = lane & 15, quad = lane >> 4;
    const int m0 = blockIdx.x * 128;
    const int n0 = blockIdx.y * 128;
    const int wm = (wave >> 1) * 64, wn = (wave & 1) * 64;

    // stage B: wt1h rows are 96 fp16 contiguous -> 12 chunks of 8
    for (int c = tid; c < 1536; c += 256) {
        int r = c / 12, ch = c % 12;
        uint4 v = *(const uint4*)(wt1h + (size_t)(n0 + r) * 96 + ch * 8);
        *(uint4*)(&Bsm[r * 104 + ch * 8]) = v;
    }
    // stage A: im2col rows (m, kh) -> 9 fp16
    for (int s = 0; s < 5; ++s) {
        int id = s * 256 + tid;
        if (id < 1152) {
            int m_l = id & 127, kh = id >> 7;
            int m = m0 + m_l;
            int b = m / 400, sp = m % 400;
            int oh = sp / 20, ow = sp % 20;
            const unsigned short* src = xh + b * 784 + (oh + kh) * 28 + ow;
            unsigned short* drow = &Asm[m_l * 104 + kh * 9];
#pragma unroll
            for (int w = 0; w < 9; ++w) drow[w] = src[w];
        }
    }
    // zero pad k in [81,96)
    for (int z = tid; z < 1920; z += 256) {
        int r = z / 15, kk = 81 + z % 15;
        Asm[r * 104 + kk] = 0;
    }
    __syncthreads();

    f32x4 acc[4][4];
#pragma unroll
    for (int i = 0; i < 4; ++i)
#pragma unroll
        for (int j = 0; j < 4; ++j) acc[i][j] = (f32x4)(0.f);

#pragma unroll
    for (int ks = 0; ks < 3; ++ks) {
        int k0 = (ks * 4 + quad) * 8;
        f16x8 af[4], bfr[4];
#pragma unroll
        for (int i = 0; i < 4; ++i)
            af[i] = *(const f16x8*)&Asm[(wm + i * 16 + ln15) * 104 + k0];
#pragma unroll
        for (int j = 0; j < 4; ++j)
            bfr[j] = *(const f16x8*)&Bsm[(wn + j * 16 + ln15) * 104 + k0];
#pragma unroll
        for (int i = 0; i < 4; ++i)
#pragma unroll
            for (int j = 0; j < 4; ++j)
                acc[i][j] = __builtin_amdgcn_mfma_f32_16x16x32_f16(
                    af[i], bfr[j], acc[i][j], 0, 0, 0);
    }

    float bias[4];
#pragma unroll
    for (int j = 0; j < 4; ++j) bias[j] = b1[n0 + wn + j * 16 + ln15];
#pragma unroll
    for (int i = 0; i < 4; ++i) {
#pragma unroll
        for (int r = 0; r < 4; ++r) {
            int m = m0 + wm + i * 16 + quad * 4 + r;
            unsigned short* dst = h1 + (size_t)m * 256 + n0 + wn;
#pragma unroll
            for (int j = 0; j < 4; ++j) {
                float v = acc[i][j][r] + bias[j];
                dst[j * 16 + ln15] = f2bf(v > 0.f ? v : 0.f);
            }
        }
    }
}

// ---------------------------------------------------------------------------
// conv2 as bf16 MFMA GEMM: M=18432, N=256, K=20736. BM=128 BN=128 BK=64,
// split-K=4 into 4 separate slices (NO atomics), gld_lds w16 + XOR swizzle.
// Slice z layout: h2a[z][m][n] fp32, coalesced stores.
__global__ __launch_bounds__(256) void k_conv2(const unsigned short* __restrict__ h1,
                                               const unsigned short* __restrict__ wt2t,
                                               float* __restrict__ h2a) {
    __shared__ short Asm[128 * 64];
    __shared__ short Bsm[128 * 64];

    const int tid  = threadIdx.x;
    const int wave = tid >> 6, lane = tid & 63;
    const int ln15 = lane & 15, quad = lane >> 4, ln7 = lane & 7;
    const int m0 = blockIdx.x * 128;
    const int n0 = blockIdx.y * 128;
    const int kt0 = blockIdx.z * 81;          // 324 kt total / 4
    const int wm = (wave >> 1) * 64, wn = (wave & 1) * 64;

    const int rbase = wave * 32 + (lane >> 3);
    const int cswz8 = ((lane & 7) ^ ((lane >> 3) & 7)) * 8;

    size_t aptr[4];
    size_t bptr[4];
#pragma unroll
    for (int s = 0; s < 4; ++s) {
        int r = rbase + s * 8;
        int m = m0 + r;
        int b = m / 36, sp = m % 36;
        int oh = sp / 6, ow = sp % 6;
        aptr[s] = (size_t)((b * 20 + 2 * oh) * 20 + 2 * ow) * 256 + cswz8;
        bptr[s] = (size_t)(n0 + r) * 20736 + cswz8;
    }
    short* alds = &Asm[(wave * 32) * 64 + lane * 8];
    short* blds = &Bsm[(wave * 32) * 64 + lane * 8];

    f32x4 acc[4][4];
#pragma unroll
    for (int i = 0; i < 4; ++i)
#pragma unroll
        for (int j = 0; j < 4; ++j) acc[i][j] = (f32x4)(0.f);

    for (int kt = kt0; kt < kt0 + 81; ++kt) {
        int q = kt >> 2;
        int kh = q / 9, kw = q - kh * 9;
        size_t aoff = (size_t)(kh * 20 + kw) * 256 + ((kt & 3) << 6);
        size_t boff = (size_t)kt << 6;
#pragma unroll
        for (int s = 0; s < 4; ++s)
            gld_lds16(h1 + aptr[s] + aoff, alds + s * 512);
#pragma unroll
        for (int s = 0; s < 4; ++s)
            gld_lds16(wt2t + bptr[s] + boff, blds + s * 512);
        __syncthreads();
#pragma unroll
        for (int ks = 0; ks < 2; ++ks) {
            bf16x8 af[4], bfr[4];
#pragma unroll
            for (int i = 0; i < 4; ++i) {
                int chunk = ((ks << 2) + quad) ^ ln7;
                af[i] = *(const bf16x8*)&Asm[(wm + i * 16 + ln15) * 64 + chunk * 8];
            }
#pragma unroll
            for (int j = 0; j < 4; ++j) {
                int chunk = ((ks << 2) + quad) ^ ln7;
                bfr[j] = *(const bf16x8*)&Bsm[(wn + j * 16 + ln15) * 64 + chunk * 8];
            }
#pragma unroll
            for (int i = 0; i < 4; ++i)
#pragma unroll
                for (int j = 0; j < 4; ++j)
                    acc[i][j] = __builtin_amdgcn_mfma_f32_16x16x32_bf16(
                        af[i], bfr[j], acc[i][j], 0, 0, 0);
        }
        __syncthreads();
    }

    // plain coalesced stores into this z's slice
    float* zs = h2a + (size_t)blockIdx.z * 4718592;
#pragma unroll
    for (int i = 0; i < 4; ++i) {
#pragma unroll
        for (int r = 0; r < 4; ++r) {
            int m = m0 + wm + i * 16 + quad * 4 + r;
            float* dst = zs + (size_t)m * 256 + n0 + wn;
#pragma unroll
            for (int j = 0; j < 4; ++j)
                dst[j * 16 + ln15] = acc[i][j][r];
        }
    }
}

// ---------------------------------------------------------------------------
// Sum 4 split-K slices + bias, squash capsules (NCHW-flatten groups of 8),
// write u[b][i][8]. One block per b; LDS tile handles the [sp][c] transpose.
__global__ __launch_bounds__(256) void k_squash(const float* __restrict__ h2a,
                                                const float* __restrict__ pb,
                                                float* __restrict__ u) {
    __shared__ float tile[36 * 260];
    const int tid = threadIdx.x;
    const int b = blockIdx.x;
    const float* base = h2a + (size_t)b * 36 * 256;
    for (int idx = tid; idx < 9216; idx += 256) {
        int sp = idx >> 8, c = idx & 255;
        float v = pb[c];
#pragma unroll
        for (int z = 0; z < 4; ++z) v += base[(size_t)z * 4718592 + sp * 256 + c];
        tile[sp * 260 + c] = v;
    }
    __syncthreads();
    for (int i2 = tid; i2 < 1152; i2 += 256) {
        int f0 = i2 * 8;
        float val[8];
        float n2 = 0.f;
#pragma unroll
        for (int e = 0; e < 8; ++e) {
            int f = f0 + e;
            int c = f / 36, sp = f - c * 36;
            val[e] = tile[sp * 260 + c];
            n2 += val[e] * val[e];
        }
        float n = sqrtf(n2);
        float s = n2 / (1.f + n2) / (n + EPS);
#pragma unroll
        for (int e = 0; e < 8; ++e) val[e] *= s;
        float* dst = u + (size_t)b * 9216 + f0;
        *(float4*)dst       = *(float4*)val;
        *(float4*)(dst + 4) = *(float4*)(val + 4);
    }
}

// ---------------------------------------------------------------------------
// Materialize x_hat[b][o][i][d] fp16 + s0[b][o][d] = sum_i xh. One block per
// b; u staged in LDS once, o-loop inside (cwh stays L2-hot).
__global__ __launch_bounds__(256) void k_xhat(const float* __restrict__ u,
                                              const __half* __restrict__ cwh,
                                              __half* __restrict__ xhat,
                                              float* __restrict__ s0) {
    __shared__ float ush[9216];
    __shared__ float part[4][16];
    const int b = blockIdx.x;
    const int t = threadIdx.x;
    const int wave = t >> 6;
    {
        const float4* src = (const float4*)(u + (size_t)b * 9216);
        float4* dst = (float4*)ush;
        for (int idx = t; idx < 2304; idx += 256) dst[idx] = src[idx];
    }
    __syncthreads();

    for (int o = 0; o < 10; ++o) {
        float s_loc[16];
#pragma unroll
        for (int d = 0; d < 16; ++d) s_loc[d] = 0.f;
        for (int i = t; i < 1152; i += 256) {
            float ui[8];
            *(float4*)ui       = *(const float4*)&ush[i * 8];
            *(float4*)(ui + 4) = *(const float4*)&ush[i * 8 + 4];
            const uint4* wp = (const uint4*)(cwh + ((size_t)(o * 1152 + i) << 7));
            unsigned short xv[16];
#pragma unroll
            for (int d = 0; d < 16; ++d) {
                float f[8];
                h8tof(wp[d], f);
                float xh = f[0] * ui[0] + f[1] * ui[1] + f[2] * ui[2] + f[3] * ui[3]
                         + f[4] * ui[4] + f[5] * ui[5] + f[6] * ui[6] + f[7] * ui[7];
                s_loc[d] += xh;
                xv[d] = f2h(xh);
            }
            __half* dst = xhat + ((size_t)((b * 10 + o) * 1152 + i)) * 16;
            *(uint4*)dst       = *(uint4*)xv;
            *(uint4*)(dst + 8) = *(uint4*)(xv + 8);
        }
#pragma unroll
        for (int off = 32; off > 0; off >>= 1)
#pragma unroll
            for (int d = 0; d < 16; ++d) s_loc[d] += __shfl_down(s_loc[d], off, 64);
        if ((t & 63) == 0) {
#pragma unroll
            for (int d = 0; d < 16; ++d) part[wave][d] = s_loc[d];
        }
        __syncthreads();
        if (t < 16)
            s0[(b * 10 + o) * 16 + t] = part[0][t] + part[1][t] + part[2][t] + part[3][t];
        __syncthreads();
    }
}

// ---------------------------------------------------------------------------
// Dynamic routing v3 (unchanged from round 4): fp16 x_hat, pass0 via s0,
// one fused sweep per pass, xh in registers across barriers.
__global__ __launch_bounds__(640) void k_routing(const __half* __restrict__ xhat,
                                                 const float* __restrict__ s0,
                                                 float* __restrict__ out) {
    __shared__ float dots[10][1152];
    __shared__ float sv[10][16];
    __shared__ float vsum[10][16];
    __shared__ float scale_sh[10];
    const int t = threadIdx.x;
    const int b = blockIdx.x;
    const int o = t >> 6, lane = t & 63;
    const __half* xb = xhat + ((size_t)(b * 10 + o) * 1152) * 16;

    if (t < 160) {
        int oo = t >> 4, d = t & 15;
        sv[oo][d] = 0.1f * s0[(b * 10 + oo) * 16 + d];
    }
    __syncthreads();
    if (t < 10) {
        float n2 = 0.f;
#pragma unroll
        for (int d = 0; d < 16; ++d) n2 += sv[t][d] * sv[t][d];
        float n = sqrtf(n2);
        scale_sh[t] = n2 / (1.f + n2) / (n + EPS);
    }
    __syncthreads();
    if (t < 160) vsum[t >> 4][t & 15] = sv[t >> 4][t & 15] * scale_sh[t >> 4];
    __syncthreads();

    for (int pass = 1; pass <= 2; ++pass) {
        float vs[16];
#pragma unroll
        for (int d = 0; d < 16; ++d) vs[d] = vsum[o][d];
        float s_loc[16];
#pragma unroll
        for (int d = 0; d < 16; ++d) s_loc[d] = 0.f;

        for (int g = 0; g < 6; ++g) {
            uint4 xq[3][2];
#pragma unroll
            for (int j = 0; j < 3; ++j) {
                int i = g * 192 + j * 64 + lane;
                const uint4* p = (const uint4*)(xb + (size_t)i * 16);
                xq[j][0] = p[0];
                xq[j][1] = p[1];
                float f0[8], f1[8];
                h8tof(xq[j][0], f0);
                h8tof(xq[j][1], f1);
                float dd = 0.f;
#pragma unroll
                for (int d = 0; d < 8; ++d) dd += vs[d] * f0[d] + vs[d + 8] * f1[d];
                dots[o][i] = dd;
            }
            __syncthreads();
            if (t < 192) {
                int i = g * 192 + t;
                float dv[10];
#pragma unroll
                for (int oo = 0; oo < 10; ++oo) dv[oo] = dots[oo][i];
                float mx = dv[0];
#pragma unroll
                for (int oo = 1; oo < 10; ++oo) mx = fmaxf(mx, dv[oo]);
                float se = 0.f;
#pragma unroll
                for (int oo = 0; oo < 10; ++oo) { dv[oo] = __expf(dv[oo] - mx); se += dv[oo]; }
                float si = 1.f / se;
#pragma unroll
                for (int oo = 0; oo < 10; ++oo) dots[oo][i] = dv[oo] * si;
            }
            __syncthreads();
#pragma unroll
            for (int j = 0; j < 3; ++j) {
                int i = g * 192 + j * 64 + lane;
                float c = dots[o][i];
                float f0[8], f1[8];
                h8tof(xq[j][0], f0);
                h8tof(xq[j][1], f1);
#pragma unroll
                for (int d = 0; d < 8; ++d) {
                    s_loc[d]     += c * f0[d];
                    s_loc[d + 8] += c * f1[d];
                }
            }
        }
#pragma unroll
        for (int off = 32; off > 0; off >>= 1)
#pragma unroll
            for (int d = 0; d < 16; ++d) s_loc[d] += __shfl_down(s_loc[d], off, 64);
        if (lane == 0) {
#pragma unroll
            for (int d = 0; d < 16; ++d) sv[o][d] = s_loc[d];
        }
        __syncthreads();
        if (pass == 1) {
            if (t < 10) {
                float n2 = 0.f;
#pragma unroll
                for (int d = 0; d < 16; ++d) n2 += sv[t][d] * sv[t][d];
                float n = sqrtf(n2);
                scale_sh[t] = n2 / (1.f + n2) / (n + EPS);
            }
            __syncthreads();
            if (t < 160) {
                int oo = t >> 4, d = t & 15;
                vsum[oo][d] += sv[oo][d] * scale_sh[oo];
            }
            __syncthreads();
        } else {
            if (t < 10) {
                float n2 = 0.f;
#pragma unroll
                for (int d = 0; d < 16; ++d) n2 += sv[t][d] * sv[t][d];
                float n = sqrtf(n2);
                out[b * 10 + t] = (n2 / (1.f + n2)) * (n / (n + EPS));
            }
        }
    }
}

// ---------------------------------------------------------------------------
extern "C" void kernel_launch(void* const* d_in, const int* in_sizes, int n_in,
                              void* d_out, int out_size, void* d_ws, size_t ws_size,
                              hipStream_t stream) {
    const float* x  = (const float*)d_in[0];   // [512,1,28,28]
    const float* w1 = (const float*)d_in[1];   // [256,1,9,9]
    const float* b1 = (const float*)d_in[2];   // [256]
    const float* pw = (const float*)d_in[3];   // [256,256,9,9]
    const float* pb = (const float*)d_in[4];   // [256]
    const float* cw = (const float*)d_in[5];   // [10,1152,16,8]
    float* out = (float*)d_out;                // [512,10]

    char* ws = (char*)d_ws;
    // Timeline aliasing: xhat (189 MB) overlays h1 (100 MB) + h2a (75.5 MB)
    // + start of wt2t -- all dead before k_xhat writes.
    unsigned short* h1   = (unsigned short*)ws;                    // 104,857,600 B @ 0
    float*          h2a  = (float*)(ws + 104857600);               //  75,497,472 B -> 180,355,072
    unsigned short* wt2t = (unsigned short*)(ws + 180355072);      //  10,616,832 B -> 190,971,904
    __half*         xhat = (__half*)ws;                            // 188,743,680 B @ 0 (alias)
    float*          u    = (float*)(ws + 190971904);               //  18,874,368 B -> 209,846,272
    __half*         cwh  = (__half*)(ws + 209846272);              //   2,949,120 B -> 212,795,392
    unsigned short* xh16 = (unsigned short*)(ws + 212795392);      //     802,816 B -> 213,598,208
    unsigned short* wt1h = (unsigned short*)(ws + 213598208);      //      49,152 B -> 213,647,360
    float*          s0   = (float*)(ws + 213647360);               //     327,680 B -> 213,975,040

    k_cast_x<<<1568, 256, 0, stream>>>(x, xh16);
    k_tw1h<<<96, 256, 0, stream>>>(w1, wt1h);
    k_tw2<<<20736, 256, 0, stream>>>(pw, wt2t);
    k_cwh<<<5760, 256, 0, stream>>>(cw, cwh);
    k_conv1<<<dim3(1600, 2), 256, 0, stream>>>(xh16, wt1h, b1, h1);
    k_conv2<<<dim3(144, 2, 4), 256, 0, stream>>>(h1, wt2t, h2a);
    k_squash<<<512, 256, 0, stream>>>(h2a, pb, u);
    k_xhat<<<512, 256, 0, stream>>>(u, cwh, xhat, s0);
    k_routing<<<512, 640, 0, stream>>>(xhat, s0, out);
}